// Round 1
// baseline (92.261 us; speedup 1.0000x reference)
//
#include <hip/hip_runtime.h>

// AggregationLayer2: out[b,h,w,c] = sum_{k=0..24} attn[b,h,w,k] * ref_value[b, h+di-2, w+dj-2, c]
//                                 + attn[b,h,w,25] * current_ref_value[b,h,w,c]
// Shapes: attn [4,128,128,26] f32, ref_value/current_ref_value/out [4,128,128,64] f32.
// SAME zero padding handled by zeroing the weight for out-of-bounds neighbors
// (index clamped so the load stays in-bounds; contribution is exactly 0).

#define KS     5
#define NSLOT  26      // 5*5 + 1
#define BINS   64
#define PIX_PER_BLOCK 16   // 256 threads / 16 threads-per-pixel

__global__ __launch_bounds__(256) void agg_kernel(
    const float* __restrict__ attn,
    const float* __restrict__ ref,
    const float* __restrict__ cur,
    float* __restrict__ out,
    int B, int H, int W)
{
    __shared__ float s_attn[PIX_PER_BLOCK * NSLOT];  // 416 floats

    const int tid = threadIdx.x;
    const int block_pix0 = blockIdx.x * PIX_PER_BLOCK;

    // Stage attn for this block's 16 pixels: 416 floats = 104 float4, coalesced.
    if (tid < (PIX_PER_BLOCK * NSLOT / 4)) {
        ((float4*)s_attn)[tid] =
            ((const float4*)(attn + (size_t)block_pix0 * NSLOT))[tid];
    }
    __syncthreads();

    const int pix_local = tid >> 4;   // 0..15
    const int q         = tid & 15;   // bin group: bins [4q, 4q+4)
    const int pix = block_pix0 + pix_local;

    const int w  = pix % W;
    const int hw = pix / W;
    const int h  = hw % H;
    const int b  = hw / H;

    const float* wv = s_attn + pix_local * NSLOT;
    const int binoff = q * 4;

    float4 acc = make_float4(0.f, 0.f, 0.f, 0.f);

    const size_t row_base = ((size_t)b * H) * W;  // pixel index of (b,0,0)

#pragma unroll
    for (int di = 0; di < KS; ++di) {
        const int hh  = h + di - 2;
        const bool hok = (hh >= 0) && (hh < H);
        const int hc  = min(max(hh, 0), H - 1);
        const size_t hrow = (row_base + (size_t)hc * W);
#pragma unroll
        for (int dj = 0; dj < KS; ++dj) {
            const int ww  = w + dj - 2;
            const bool ok = hok && (ww >= 0) && (ww < W);
            const int wc  = min(max(ww, 0), W - 1);
            const float wgt = ok ? wv[di * KS + dj] : 0.0f;
            const float4 v = *(const float4*)(ref + (hrow + wc) * BINS + binoff);
            acc.x += wgt * v.x;
            acc.y += wgt * v.y;
            acc.z += wgt * v.z;
            acc.w += wgt * v.w;
        }
    }

    // slot 25: current_ref_value
    {
        const float wgt = wv[KS * KS];
        const float4 v = *(const float4*)(cur + (size_t)pix * BINS + binoff);
        acc.x += wgt * v.x;
        acc.y += wgt * v.y;
        acc.z += wgt * v.z;
        acc.w += wgt * v.w;
    }

    *(float4*)(out + (size_t)pix * BINS + binoff) = acc;
}

extern "C" void kernel_launch(void* const* d_in, const int* in_sizes, int n_in,
                              void* d_out, int out_size, void* d_ws, size_t ws_size,
                              hipStream_t stream) {
    const float* attn = (const float*)d_in[0];
    const float* ref  = (const float*)d_in[1];
    const float* cur  = (const float*)d_in[2];
    float* out = (float*)d_out;

    const int B = 4, H = 128, W = 128;
    const int pixels = B * H * W;                 // 65536
    const int blocks = pixels / PIX_PER_BLOCK;    // 4096

    agg_kernel<<<blocks, 256, 0, stream>>>(attn, ref, cur, out, B, H, W);
}

// Round 2
// 91.483 us; speedup vs baseline: 1.0085x; 1.0085x over previous
//
#include <hip/hip_runtime.h>

// AggregationLayer2: out[b,h,w,c] = sum_{di,dj} attn[b,h,w,di*5+dj] * ref[b, h+di-2, w+dj-2, c]
//                                 + attn[b,h,w,25] * cur[b,h,w,c]
// attn [4,128,128,26] f32; ref/cur/out [4,128,128,64] f32. SAME zero padding.
//
// Strategy: block = 16(w) x 4(h) pixel tile, 256 threads.
//   tid&15  = q  -> bin group (4 consecutive bins, float4)   [coalescing: q innermost]
//   tid>>4  = wg -> w offset in tile
//   each thread accumulates 4 vertically-adjacent pixels -> the 5x5 windows share
//   rows, so only an 8-row x 5-col window of ref is loaded (40 float4 per thread
//   for 4 pixels = 2.5x fewer loads than 1-pixel-per-thread).
// Weights staged to LDS transposed as s_w[rl][di][wl][8] (dj 0..4 in an aligned
// 8-float slot) with OOB-*column* weights zeroed at staging time -> main loop has
// zero predication. OOB *rows* are skipped with a block-uniform branch.

#define KS    5
#define NSLOT 26
#define BINS  64
#define TW    16
#define TH    4

__global__ __launch_bounds__(256) void agg_kernel(
    const float* __restrict__ attn,
    const float* __restrict__ ref,
    const float* __restrict__ cur,
    float* __restrict__ out)
{
    constexpr int H = 128, W = 128;

    __shared__ __align__(16) float s_w[TH * KS * TW * 8];  // 2560 f = 10 KiB
    __shared__ float s_w25[TH * TW];                        // 64 f

    const int tid = threadIdx.x;
    const int blk = blockIdx.x;            // [b][htile][wtile] : 4*32*8 = 1024
    const int w0 = (blk & 7) * TW;
    const int h0 = ((blk >> 3) & 31) * TH;
    const int b  = blk >> 8;

    const size_t pix00 = ((size_t)b * H + h0) * W + w0;  // pixel idx of (b,h0,w0)

    // ---- stage attn (64 px x 26 slots) into transposed LDS ----
    for (int i = tid; i < TH * TW * NSLOT; i += 256) {
        const int rl   = i / (TW * NSLOT);
        const int rem  = i - rl * (TW * NSLOT);
        const int wl   = rem / NSLOT;
        const int slot = rem - wl * NSLOT;
        float v = attn[(pix00 + (size_t)rl * W + wl) * NSLOT + slot];
        if (slot == NSLOT - 1) {
            s_w25[rl * TW + wl] = v;
        } else {
            const int di = slot / KS;
            const int dj = slot - di * KS;
            const int ww = w0 + wl - 2 + dj;
            if (ww < 0 || ww >= W) v = 0.0f;   // zero-pad columns folded into weight
            s_w[((rl * KS + di) * TW + wl) * 8 + dj] = v;
        }
    }
    __syncthreads();

    const int wg = tid >> 4;       // w offset 0..15
    const int q  = tid & 15;       // bin group 0..15
    const int binoff = q * 4;
    const int w = w0 + wg;

    // clamped column offsets (element offsets into a ref row), OOB weight already 0
    int wcoff[KS];
#pragma unroll
    for (int dj = 0; dj < KS; ++dj) {
        int ww = w - 2 + dj;
        ww = min(max(ww, 0), W - 1);
        wcoff[dj] = ww * BINS + binoff;
    }

    float4 acc[TH];
#pragma unroll
    for (int rl = 0; rl < TH; ++rl) acc[rl] = make_float4(0.f, 0.f, 0.f, 0.f);

    const size_t brow = (size_t)b * H * W;   // pixel idx of (b,0,0)

#pragma unroll
    for (int hi = 0; hi < TH + 4; ++hi) {    // hh = h0-2+hi, 8 window rows
        const int hh = h0 - 2 + hi;
        if (hh < 0 || hh >= H) continue;     // block-uniform (h0 uniform): zero-pad rows
        const float* rowp = ref + (brow + (size_t)hh * W) * BINS;

        float4 v[KS];
#pragma unroll
        for (int dj = 0; dj < KS; ++dj)
            v[dj] = *(const float4*)(rowp + wcoff[dj]);

#pragma unroll
        for (int rl = 0; rl < TH; ++rl) {
            const int di = hi - rl;          // compile-time per unrolled iter
            if (di < 0 || di > 4) continue;
            const float* wp = &s_w[((rl * KS + di) * TW + wg) * 8];
            const float4 w03 = *(const float4*)wp;
            const float  w4  = wp[4];
            acc[rl].x += w03.x * v[0].x + w03.y * v[1].x + w03.z * v[2].x + w03.w * v[3].x + w4 * v[4].x;
            acc[rl].y += w03.x * v[0].y + w03.y * v[1].y + w03.z * v[2].y + w03.w * v[3].y + w4 * v[4].y;
            acc[rl].z += w03.x * v[0].z + w03.y * v[1].z + w03.z * v[2].z + w03.w * v[3].z + w4 * v[4].z;
            acc[rl].w += w03.x * v[0].w + w03.y * v[1].w + w03.z * v[2].w + w03.w * v[3].w + w4 * v[4].w;
        }
    }

    // ---- slot 25 (current value) + store ----
#pragma unroll
    for (int rl = 0; rl < TH; ++rl) {
        const float wgt = s_w25[rl * TW + wg];
        const size_t p = pix00 + (size_t)rl * W + wg;
        const float4 v = *(const float4*)(cur + p * BINS + binoff);
        float4 a = acc[rl];
        a.x += wgt * v.x;
        a.y += wgt * v.y;
        a.z += wgt * v.z;
        a.w += wgt * v.w;
        *(float4*)(out + p * BINS + binoff) = a;
    }
}

extern "C" void kernel_launch(void* const* d_in, const int* in_sizes, int n_in,
                              void* d_out, int out_size, void* d_ws, size_t ws_size,
                              hipStream_t stream) {
    const float* attn = (const float*)d_in[0];
    const float* ref  = (const float*)d_in[1];
    const float* cur  = (const float*)d_in[2];
    float* out = (float*)d_out;

    // B=4, H=128, W=128 -> 4 * (128/4) * (128/16) = 1024 blocks
    agg_kernel<<<1024, 256, 0, stream>>>(attn, ref, cur, out);
}